// Round 7
// baseline (81.269 us; speedup 1.0000x reference)
//
#include <hip/hip_runtime.h>

#define VOCAB 100000
#define EMB   20
#define HID   10
#define SEQ   100
#define NLAB  15
#define BATCH 16384
#define GATES 40
#define PROWF 40   // f32 per row; slot = u*4 + G (unit-major). main: float4 @ sub*4; extra: @ 32+(sub&1)*4

__device__ __forceinline__ float exp2_f(float x){ float r; asm("v_exp_f32 %0, %1" : "=v"(r) : "v"(x)); return r; }
__device__ __forceinline__ float rcp_f(float x){ float r; asm("v_rcp_f32 %0, %1" : "=v"(r) : "v"(x)); return r; }

// Gate scales folded into P/Wh/bias: sigmoid(x)=rcp(1+exp2(-log2e*x)),
// tanh(x)=(1-E)/(1+E), E=exp2(-2log2e*x). c-gate scale -2log2e, others -log2e.
__device__ __host__ __forceinline__ constexpr float gscale(int G){
  return (G == 2) ? -2.885390081777927f : -1.442695040888963f;
}

// broadcast within each 8-lane group: src lane = (lane & 0x18) | K   (BitMode: and=0x18, or=K, xor=0)
template<int OFF>
__device__ __forceinline__ float bswz(float x){
  return __int_as_float(__builtin_amdgcn_ds_swizzle(__float_as_int(x), OFF));
}

template<int CTRL>
__device__ __forceinline__ float qb(float x){
  return __int_as_float(__builtin_amdgcn_mov_dpp(__float_as_int(x), CTRL, 0xF, 0xF, true));
}

// -------- P = (embed @ Wx + b) * gate_scale, f32, [VOCAB][40]: slot = u*4 + G
__global__ __launch_bounds__(256)
void proj_kernel_f32(const float* __restrict__ emb, const float* __restrict__ Wx,
                     const float* __restrict__ bias, float* __restrict__ P)
{
  __shared__ float Wxl[EMB * PROWF];
  __shared__ float bl[PROWF];
  const int tid = threadIdx.x;
  for (int i = tid; i < EMB * PROWF; i += 256) {
    int k = i / PROWF, slot = i - k * PROWF;
    int u = slot >> 2, G = slot & 3;
    Wxl[i] = Wx[k * GATES + G * HID + u] * gscale(G);
  }
  if (tid < PROWF) {
    int u = tid >> 2, G = tid & 3;
    bl[tid] = bias[G * HID + u] * gscale(G);
  }
  __syncthreads();

  const int v   = blockIdx.x * 32 + (tid >> 3);
  const int sub = tid & 7;
  if (v >= VOCAB) return;

  const float4* er = (const float4*)(emb + (size_t)v * EMB);
  float4 e0 = er[0], e1 = er[1], e2 = er[2], e3 = er[3], e4 = er[4];
  float e[EMB] = {e0.x,e0.y,e0.z,e0.w, e1.x,e1.y,e1.z,e1.w, e2.x,e2.y,e2.z,e2.w,
                  e3.x,e3.y,e3.z,e3.w, e4.x,e4.y,e4.z,e4.w};
  const int wb = sub * 5;               // 5 slots per thread
  float acc[5];
  #pragma unroll
  for (int c = 0; c < 5; ++c) acc[c] = bl[wb + c];
  #pragma unroll
  for (int k = 0; k < EMB; ++k)
    #pragma unroll
    for (int c = 0; c < 5; ++c)
      acc[c] = fmaf(e[k], Wxl[k * PROWF + wb + c], acc[c]);
  float* o = P + (size_t)v * PROWF + wb;
  #pragma unroll
  for (int c = 0; c < 5; ++c) o[c] = acc[c];
}

// -------- 8-lane-per-element LSTM, full f32. Lane sub owns unit sub; lanes 0,1 also own units 8,9.
__global__ __launch_bounds__(256, 2)
void rnn8f_kernel(const int* __restrict__ x, const float* __restrict__ P,
                  const float* __restrict__ Wh, const float* __restrict__ Wd,
                  const float* __restrict__ bd, float* __restrict__ out)
{
  __shared__ int xs[32 * SEQ];
  const int tid = threadIdx.x;
  const int grp = tid >> 3;      // local element 0..31
  const int sub = tid & 7;
  const int b0  = blockIdx.x * 32;

  for (int i = tid; i < 32 * SEQ; i += 256) xs[i] = x[(size_t)b0 * SEQ + i];

  // f32 recurrent weights: main unit (all lanes) + extra unit (lanes 0,1; zeros elsewhere)
  const int ux = 8 + (sub & 1);
  float wm[HID][4], wx[HID][4];
  #pragma unroll
  for (int k = 0; k < HID; ++k)
    #pragma unroll
    for (int G = 0; G < 4; ++G) {
      wm[k][G] = Wh[k * GATES + G * HID + sub] * gscale(G);
      wx[k][G] = (sub < 2) ? Wh[k * GATES + G * HID + ux] * gscale(G) : 0.f;
    }

  __syncthreads();

  float cm = 0.f, cx = 0.f;      // cell states: main unit, extra unit
  float h[HID];
  #pragma unroll
  for (int k = 0; k < HID; ++k) h[k] = 0.f;

  const int* xrow = xs + grp * SEQ;

  float4 mA, xA, mB, xB, mC, xC;
  auto ldrow = [&](float4& m, float4& xq, int t) {
    int tt = t < SEQ ? t : SEQ - 1;
    const float* rp = P + (size_t)xrow[tt] * PROWF;
    m  = *(const float4*)(rp + sub * 4);             // unit sub: i,f,c,o
    xq = *(const float4*)(rp + 32 + (sub & 1) * 4);  // unit 8+(sub&1): i,f,c,o
  };
  ldrow(mA, xA, 0); ldrow(mB, xB, 1); ldrow(mC, xC, 2);

  auto step = [&](float4& m, float4& xq, int t) {
    float zm[4] = {m.x, m.y, m.z, m.w};
    float zx[4] = {xq.x, xq.y, xq.z, xq.w};
    ldrow(m, xq, t + 3);                 // depth-3 prefetch

    #pragma unroll
    for (int k = 0; k < HID; ++k) {
      #pragma unroll
      for (int G = 0; G < 4; ++G) {
        zm[G] = fmaf(h[k], wm[k][G], zm[G]);
        zx[G] = fmaf(h[k], wx[k][G], zx[G]);
      }
    }

    // main unit activation (merged-rcp, scales pre-folded)
    float hm;
    {
      float Ei = exp2_f(zm[0]);
      float Ef = exp2_f(zm[1]);
      float Ec = exp2_f(fminf(zm[2], 60.f));
      float Eo = exp2_f(zm[3]);
      float f  = rcp_f(1.f + Ef);
      float ig = (1.f - Ec) * rcp_f((1.f + Ei) * (1.f + Ec));
      cm = fmaf(f, cm, ig);
      float Et = exp2_f(fminf(-2.885390081777927f * cm, 60.f));
      hm = (1.f - Et) * rcp_f((1.f + Eo) * (1.f + Et));
    }
    // extra unit (meaningful on lanes 0,1; bounded garbage elsewhere, never broadcast)
    float hx;
    {
      float Ei = exp2_f(zx[0]);
      float Ef = exp2_f(zx[1]);
      float Ec = exp2_f(fminf(zx[2], 60.f));
      float Eo = exp2_f(zx[3]);
      float f  = rcp_f(1.f + Ef);
      float ig = (1.f - Ec) * rcp_f((1.f + Ei) * (1.f + Ec));
      cx = fmaf(f, cx, ig);
      float Et = exp2_f(fminf(-2.885390081777927f * cx, 60.f));
      hx = (1.f - Et) * rcp_f((1.f + Eo) * (1.f + Et));
    }

    // f32 broadcast across the 8-lane group
    h[0] = bswz<0x18>(hm); h[1] = bswz<0x38>(hm);
    h[2] = bswz<0x58>(hm); h[3] = bswz<0x78>(hm);
    h[4] = bswz<0x98>(hm); h[5] = bswz<0xB8>(hm);
    h[6] = bswz<0xD8>(hm); h[7] = bswz<0xF8>(hm);
    h[8] = bswz<0x18>(hx); h[9] = bswz<0x38>(hx);
  };

  #pragma unroll 1
  for (int t = 0; t < SEQ - 1; t += 3) {   // 33 triples: t = 0..98
    step(mA, xA, t);
    step(mB, xB, t + 1);
    step(mC, xC, t + 2);
  }
  step(mA, xA, SEQ - 1);                   // t = 99

  // dense head from f32 h
  #pragma unroll
  for (int s2 = 0; s2 < 2; ++s2) {
    int j = s2 * 8 + sub;
    if (j < NLAB) {
      float acc = bd[j];
      #pragma unroll
      for (int k = 0; k < HID; ++k)
        acc = fmaf(h[k], Wd[k * NLAB + j], acc);
      out[(size_t)(b0 + grp) * NLAB + j] = acc;
    }
  }
}

// -------- fallback (ws too small for P): 4-lane on-the-fly f32 path
__global__ __launch_bounds__(256, 1)
void rnn_kernel_fb(const int* __restrict__ x, const float* __restrict__ emb,
                   const float* __restrict__ Wx, const float* __restrict__ Wh,
                   const float* __restrict__ bias, const float* __restrict__ Wd,
                   const float* __restrict__ bd, float* __restrict__ out)
{
  __shared__ int   xs[64 * SEQ];
  __shared__ float Wxl[EMB * 48];
  __shared__ float bls[48];
  const int tid = threadIdx.x, lb = tid >> 2, sub = tid & 3, b0 = blockIdx.x * 64;
  for (int i = tid; i < 64 * SEQ; i += 256) xs[i] = x[(size_t)b0 * SEQ + i];
  for (int i = tid; i < EMB * 48; i += 256) {
    int k = i / 48, slot = i - k * 48;
    int sb2 = slot / 12, r = slot - sb2 * 12, G = r / 3, s = r - G * 3, u = s * 4 + sb2;
    Wxl[i] = (u < HID) ? Wx[k * GATES + G * HID + u] * gscale(G) : 0.f;
  }
  if (tid < 48) {
    int slot = tid, sb2 = slot / 12, r = slot - sb2 * 12, G = r / 3, s = r - G * 3, u = s * 4 + sb2;
    bls[slot] = (u < HID) ? bias[G * HID + u] * gscale(G) : 0.f;
  }
  float Whr[HID][12];
  #pragma unroll
  for (int j = 0; j < 12; ++j) {
    const int G = j / 3, s = j - G * 3, u = s * 4 + sub;
    #pragma unroll
    for (int k = 0; k < HID; ++k)
      Whr[k][j] = (u < HID) ? Wh[k * GATES + G * HID + u] * gscale(G) : 0.f;
  }
  __syncthreads();
  float cst[3] = {0.f, 0.f, 0.f};
  float h[HID];
  #pragma unroll
  for (int k = 0; k < HID; ++k) h[k] = 0.f;
  float bb[12];
  #pragma unroll
  for (int j = 0; j < 12; ++j) bb[j] = bls[sub * 12 + j];
  const int* xrow = xs + lb * SEQ;
  float4 e0, e1, e2, e3, e4;
  {
    int row = xrow[0];
    const float4* q = (const float4*)(emb + (size_t)row * EMB);
    e0 = q[0]; e1 = q[1]; e2 = q[2]; e3 = q[3]; e4 = q[4];
  }
  #pragma unroll 1
  for (int t = 0; t < SEQ; ++t) {
    float e[EMB] = {e0.x,e0.y,e0.z,e0.w, e1.x,e1.y,e1.z,e1.w, e2.x,e2.y,e2.z,e2.w,
                    e3.x,e3.y,e3.z,e3.w, e4.x,e4.y,e4.z,e4.w};
    float z[12];
    #pragma unroll
    for (int j = 0; j < 12; ++j) z[j] = bb[j];
    #pragma unroll
    for (int k = 0; k < EMB; ++k)
      #pragma unroll
      for (int j = 0; j < 12; ++j)
        z[j] = fmaf(e[k], Wxl[k * 48 + sub * 12 + j], z[j]);
    if (t + 1 < SEQ) {
      int row = xrow[t + 1];
      const float4* q = (const float4*)(emb + (size_t)row * EMB);
      e0 = q[0]; e1 = q[1]; e2 = q[2]; e3 = q[3]; e4 = q[4];
    }
    #pragma unroll
    for (int k = 0; k < HID; ++k)
      #pragma unroll
      for (int j = 0; j < 12; ++j)
        z[j] = fmaf(h[k], Whr[k][j], z[j]);
    float hl[3];
    #pragma unroll
    for (int s = 0; s < 3; ++s) {
      float Ei = exp2_f(z[s]), Ef = exp2_f(z[s+3]);
      float Ec = exp2_f(fminf(z[s+6], 60.f)), Eo = exp2_f(z[s+9]);
      float f  = rcp_f(1.f + Ef);
      float ig = (1.f - Ec) * rcp_f((1.f + Ei) * (1.f + Ec));
      cst[s] = fmaf(f, cst[s], ig);
      float Et = exp2_f(fminf(-2.885390081777927f * cst[s], 60.f));
      hl[s] = (1.f - Et) * rcp_f((1.f + Eo) * (1.f + Et));
    }
    h[0] = qb<0x00>(hl[0]); h[1] = qb<0x55>(hl[0]); h[2] = qb<0xAA>(hl[0]); h[3] = qb<0xFF>(hl[0]);
    h[4] = qb<0x00>(hl[1]); h[5] = qb<0x55>(hl[1]); h[6] = qb<0xAA>(hl[1]); h[7] = qb<0xFF>(hl[1]);
    h[8] = qb<0x00>(hl[2]); h[9] = qb<0x55>(hl[2]);
  }
  #pragma unroll
  for (int s = 0; s < 4; ++s) {
    int j = s * 4 + sub;
    if (j < NLAB) {
      float acc = bd[j];
      #pragma unroll
      for (int k = 0; k < HID; ++k)
        acc = fmaf(h[k], Wd[k * NLAB + j], acc);
      out[(size_t)(b0 + lb) * NLAB + j] = acc;
    }
  }
}

extern "C" void kernel_launch(void* const* d_in, const int* in_sizes, int n_in,
                              void* d_out, int out_size, void* d_ws, size_t ws_size,
                              hipStream_t stream) {
  (void)in_sizes; (void)n_in; (void)out_size;
  const int*   x    = (const int*)  d_in[0];
  const float* emb  = (const float*)d_in[1];
  const float* Wx   = (const float*)d_in[2];
  const float* Wh   = (const float*)d_in[3];
  const float* bias = (const float*)d_in[4];
  const float* Wd   = (const float*)d_in[5];
  const float* bd   = (const float*)d_in[6];
  float* out = (float*)d_out;

  const size_t pbytes = (size_t)VOCAB * PROWF * sizeof(float);   // 16 MB
  if (ws_size >= pbytes) {
    float* P = (float*)d_ws;
    hipLaunchKernelGGL(proj_kernel_f32, dim3((VOCAB + 31) / 32), dim3(256), 0, stream,
                       emb, Wx, bias, P);
    hipLaunchKernelGGL(rnn8f_kernel, dim3(BATCH / 32), dim3(256), 0, stream,
                       x, P, Wh, Wd, bd, out);
  } else {
    hipLaunchKernelGGL(rnn_kernel_fb, dim3(BATCH / 64), dim3(256), 0, stream,
                       x, emb, Wx, Wh, bias, Wd, bd, out);
  }
}

// Round 8
// 66.622 us; speedup vs baseline: 1.2198x; 1.2198x over previous
//
#include <hip/hip_runtime.h>
#include <hip/hip_fp16.h>

#define VOCAB 100000
#define EMB   20
#define HID   10
#define SEQ   100
#define NLAB  15
#define BATCH 16384
#define GATES 40
#define PROWH 40  // halfs/row: [u0..7 x4 gates (b64 @ 4*sub)][u8 i,f,c,o][u9 i,f,c,o] (extra half @ 32+sub)

__device__ __forceinline__ float exp2_f(float x){ float r; asm("v_exp_f32 %0, %1" : "=v"(r) : "v"(x)); return r; }
__device__ __forceinline__ float rcp_f(float x){ float r; asm("v_rcp_f32 %0, %1" : "=v"(r) : "v"(x)); return r; }

// Gate scales folded into P/Wh/bias: sigmoid(x)=rcp(1+exp2(-log2e*x)),
// tanh(x)=(1-E)/(1+E), E=exp2(-2log2e*x). c-gate scale -2log2e, others -log2e.
__device__ __host__ __forceinline__ constexpr float gscale(int G){
  return (G == 2) ? -2.885390081777927f : -1.442695040888963f;
}

// ds_swizzle BitMode: src_lane = ((lane & and) | or) ^ xor ; offset = xor<<10 | or<<5 | and
template<int OFF>
__device__ __forceinline__ float bswz(float x){
  return __int_as_float(__builtin_amdgcn_ds_swizzle(__float_as_int(x), OFF));
}

template<int CTRL>
__device__ __forceinline__ float qb(float x){
  return __int_as_float(__builtin_amdgcn_mov_dpp(__float_as_int(x), CTRL, 0xF, 0xF, true));
}

// -------- P = fp16( (embed @ Wx + b) * gate_scale ), row = 40 halfs, slot = u*4+G
__global__ __launch_bounds__(256)
void proj_kernel_h(const float* __restrict__ emb, const float* __restrict__ Wx,
                   const float* __restrict__ bias, __half* __restrict__ P)
{
  __shared__ float Wxl[EMB * GATES];   // [k][slot], slot = u*4+G
  __shared__ float bl[GATES];
  const int tid = threadIdx.x;
  for (int i = tid; i < EMB * GATES; i += 256) {
    int k = i / GATES, slot = i - k * GATES;
    int u = slot >> 2, G = slot & 3;
    Wxl[i] = Wx[k * GATES + G * HID + u] * gscale(G);
  }
  if (tid < GATES) {
    int u = tid >> 2, G = tid & 3;
    bl[tid] = bias[G * HID + u] * gscale(G);
  }
  __syncthreads();

  const int v   = blockIdx.x * 32 + (tid >> 3);
  const int sub = tid & 7;
  if (v >= VOCAB) return;

  const float4* er = (const float4*)(emb + (size_t)v * EMB);
  float4 e0 = er[0], e1 = er[1], e2 = er[2], e3 = er[3], e4 = er[4];
  float e[EMB] = {e0.x,e0.y,e0.z,e0.w, e1.x,e1.y,e1.z,e1.w, e2.x,e2.y,e2.z,e2.w,
                  e3.x,e3.y,e3.z,e3.w, e4.x,e4.y,e4.z,e4.w};

  // this lane's 5 slots: main 4*sub+c (c=0..3), extra 32+sub
  int sl[5] = {4*sub, 4*sub+1, 4*sub+2, 4*sub+3, 32+sub};
  float acc[5];
  #pragma unroll
  for (int c = 0; c < 5; ++c) acc[c] = bl[sl[c]];
  #pragma unroll
  for (int k = 0; k < EMB; ++k)
    #pragma unroll
    for (int c = 0; c < 5; ++c)
      acc[c] = fmaf(e[k], Wxl[k * GATES + sl[c]], acc[c]);

  union { __half h[4]; uint2 u2; } um;
  #pragma unroll
  for (int c = 0; c < 4; ++c) um.h[c] = __float2half(acc[c]);
  *(uint2*)(P + (size_t)v * PROWH + 4 * sub) = um.u2;
  P[(size_t)v * PROWH + 32 + sub] = __float2half(acc[4]);
}

// -------- 8-lane-per-element LSTM: f32 recurrence, fp16 P rows.
// Lane sub owns unit sub (4 gates) + one extra z-slot: unit 8+(sub>>2), gate sub&3.
__global__ __launch_bounds__(256, 2)
void rnn8h_kernel(const int* __restrict__ x, const __half* __restrict__ P,
                  const float* __restrict__ Wh, const float* __restrict__ Wd,
                  const float* __restrict__ bd, float* __restrict__ out)
{
  __shared__ int xs[32 * SEQ];
  const int tid = threadIdx.x;
  const int grp = tid >> 3;      // local element 0..31
  const int sub = tid & 7;
  const int b0  = blockIdx.x * 32;

  for (int i = tid; i < 32 * SEQ; i += 256) xs[i] = x[(size_t)b0 * SEQ + i];

  // f32 recurrent weights: main unit sub (40) + extra slot (10) = 50 regs, pinned.
  const int Ge = sub & 3;             // extra slot's gate
  const int ue = 8 + (sub >> 2);      // extra slot's unit
  float wm[HID][4], we[HID];
  #pragma unroll
  for (int k = 0; k < HID; ++k) {
    #pragma unroll
    for (int G = 0; G < 4; ++G)
      wm[k][G] = Wh[k * GATES + G * HID + sub] * gscale(G);
    we[k] = Wh[k * GATES + Ge * HID + ue] * gscale(Ge);
  }
  #pragma unroll
  for (int k = 0; k < HID; ++k) {
    #pragma unroll
    for (int G = 0; G < 4; ++G)
      asm volatile("" : "+v"(wm[k][G]));
    asm volatile("" : "+v"(we[k]));
  }

  __syncthreads();

  float cm = 0.f, cx = 0.f;           // cell states: main unit; extra unit (lanes 0-3: c8, 4-7: c9)
  float h[HID];
  #pragma unroll
  for (int k = 0; k < HID; ++k) h[k] = 0.f;

  const int* xrow = xs + grp * SEQ;

  uint2 mA, mB, mC; __half eA, eB, eC;
  auto ldrow = [&](uint2& m, __half& ex, int t) {
    int tt = t < SEQ ? t : SEQ - 1;
    const __half* rp = P + (size_t)xrow[tt] * PROWH;
    m  = *(const uint2*)(rp + 4 * sub);
    ex = rp[32 + sub];
  };
  ldrow(mA, eA, 0); ldrow(mB, eB, 1); ldrow(mC, eC, 2);

  auto step = [&](uint2& m, __half& ex, int t) {
    float zm[4], z5;
    {
      float2 a = __half22float2(*(const __half2*)&m.x);
      float2 b = __half22float2(*(const __half2*)&m.y);
      zm[0] = a.x; zm[1] = a.y; zm[2] = b.x; zm[3] = b.y;
      z5 = __half2float(ex);
    }
    ldrow(m, ex, t + 3);                 // depth-3 prefetch

    #pragma unroll
    for (int k = 0; k < HID; ++k) {
      #pragma unroll
      for (int G = 0; G < 4; ++G)
        zm[G] = fmaf(h[k], wm[k][G], zm[G]);
      z5 = fmaf(h[k], we[k], z5);
    }

    // gather extra unit gates: src = (lane & 0x1C) | G  ->  lanes 0-3 hold unit8 (i,f,c,o), 4-7 unit9
    float zx0 = bswz<0x1C>(z5);
    float zx1 = bswz<0x3C>(z5);
    float zx2 = bswz<0x5C>(z5);
    float zx3 = bswz<0x7C>(z5);

    // main unit activation
    float hm;
    {
      float Ei = exp2_f(zm[0]);
      float Ef = exp2_f(zm[1]);
      float Ec = exp2_f(fminf(zm[2], 60.f));
      float Eo = exp2_f(zm[3]);
      float f  = rcp_f(1.f + Ef);
      float ig = (1.f - Ec) * rcp_f((1.f + Ei) * (1.f + Ec));
      cm = fmaf(f, cm, ig);
      float Et = exp2_f(fminf(-2.885390081777927f * cm, 60.f));
      hm = (1.f - Et) * rcp_f((1.f + Eo) * (1.f + Et));
    }
    // extra unit activation (lanes 0-3 compute h8, lanes 4-7 compute h9)
    float hx;
    {
      float Ei = exp2_f(zx0);
      float Ef = exp2_f(zx1);
      float Ec = exp2_f(fminf(zx2, 60.f));
      float Eo = exp2_f(zx3);
      float f  = rcp_f(1.f + Ef);
      float ig = (1.f - Ec) * rcp_f((1.f + Ei) * (1.f + Ec));
      cx = fmaf(f, cx, ig);
      float Et = exp2_f(fminf(-2.885390081777927f * cx, 60.f));
      hx = (1.f - Et) * rcp_f((1.f + Eo) * (1.f + Et));
    }

    // f32 broadcast across the 8-lane group (r7-verified offsets)
    h[0] = bswz<0x18>(hm); h[1] = bswz<0x38>(hm);
    h[2] = bswz<0x58>(hm); h[3] = bswz<0x78>(hm);
    h[4] = bswz<0x98>(hm); h[5] = bswz<0xB8>(hm);
    h[6] = bswz<0xD8>(hm); h[7] = bswz<0xF8>(hm);
    h[8] = bswz<0x18>(hx); h[9] = bswz<0x98>(hx);
  };

  #pragma unroll 1
  for (int t = 0; t < SEQ - 1; t += 3) {   // 33 triples: t = 0..98
    step(mA, eA, t);
    step(mB, eB, t + 1);
    step(mC, eC, t + 2);
  }
  step(mA, eA, SEQ - 1);                   // t = 99

  // dense head from f32 h
  #pragma unroll
  for (int s2 = 0; s2 < 2; ++s2) {
    int j = s2 * 8 + sub;
    if (j < NLAB) {
      float acc = bd[j];
      #pragma unroll
      for (int k = 0; k < HID; ++k)
        acc = fmaf(h[k], Wd[k * NLAB + j], acc);
      out[(size_t)(b0 + grp) * NLAB + j] = acc;
    }
  }
}

// -------- fallback (ws too small for P): 4-lane on-the-fly f32 path (r7, passing)
__global__ __launch_bounds__(256, 1)
void rnn_kernel_fb(const int* __restrict__ x, const float* __restrict__ emb,
                   const float* __restrict__ Wx, const float* __restrict__ Wh,
                   const float* __restrict__ bias, const float* __restrict__ Wd,
                   const float* __restrict__ bd, float* __restrict__ out)
{
  __shared__ int   xs[64 * SEQ];
  __shared__ float Wxl[EMB * 48];
  __shared__ float bls[48];
  const int tid = threadIdx.x, lb = tid >> 2, sub = tid & 3, b0 = blockIdx.x * 64;
  for (int i = tid; i < 64 * SEQ; i += 256) xs[i] = x[(size_t)b0 * SEQ + i];
  for (int i = tid; i < EMB * 48; i += 256) {
    int k = i / 48, slot = i - k * 48;
    int sb2 = slot / 12, r = slot - sb2 * 12, G = r / 3, s = r - G * 3, u = s * 4 + sb2;
    Wxl[i] = (u < HID) ? Wx[k * GATES + G * HID + u] * gscale(G) : 0.f;
  }
  if (tid < 48) {
    int slot = tid, sb2 = slot / 12, r = slot - sb2 * 12, G = r / 3, s = r - G * 3, u = s * 4 + sb2;
    bls[slot] = (u < HID) ? bias[G * HID + u] * gscale(G) : 0.f;
  }
  float Whr[HID][12];
  #pragma unroll
  for (int j = 0; j < 12; ++j) {
    const int G = j / 3, s = j - G * 3, u = s * 4 + sub;
    #pragma unroll
    for (int k = 0; k < HID; ++k)
      Whr[k][j] = (u < HID) ? Wh[k * GATES + G * HID + u] * gscale(G) : 0.f;
  }
  __syncthreads();
  float cst[3] = {0.f, 0.f, 0.f};
  float h[HID];
  #pragma unroll
  for (int k = 0; k < HID; ++k) h[k] = 0.f;
  float bb[12];
  #pragma unroll
  for (int j = 0; j < 12; ++j) bb[j] = bls[sub * 12 + j];
  const int* xrow = xs + lb * SEQ;
  float4 e0, e1, e2, e3, e4;
  {
    int row = xrow[0];
    const float4* q = (const float4*)(emb + (size_t)row * EMB);
    e0 = q[0]; e1 = q[1]; e2 = q[2]; e3 = q[3]; e4 = q[4];
  }
  #pragma unroll 1
  for (int t = 0; t < SEQ; ++t) {
    float e[EMB] = {e0.x,e0.y,e0.z,e0.w, e1.x,e1.y,e1.z,e1.w, e2.x,e2.y,e2.z,e2.w,
                    e3.x,e3.y,e3.z,e3.w, e4.x,e4.y,e4.z,e4.w};
    float z[12];
    #pragma unroll
    for (int j = 0; j < 12; ++j) z[j] = bb[j];
    #pragma unroll
    for (int k = 0; k < EMB; ++k)
      #pragma unroll
      for (int j = 0; j < 12; ++j)
        z[j] = fmaf(e[k], Wxl[k * 48 + sub * 12 + j], z[j]);
    if (t + 1 < SEQ) {
      int row = xrow[t + 1];
      const float4* q = (const float4*)(emb + (size_t)row * EMB);
      e0 = q[0]; e1 = q[1]; e2 = q[2]; e3 = q[3]; e4 = q[4];
    }
    #pragma unroll
    for (int k = 0; k < HID; ++k)
      #pragma unroll
      for (int j = 0; j < 12; ++j)
        z[j] = fmaf(h[k], Whr[k][j], z[j]);
    float hl[3];
    #pragma unroll
    for (int s = 0; s < 3; ++s) {
      float Ei = exp2_f(z[s]), Ef = exp2_f(z[s+3]);
      float Ec = exp2_f(fminf(z[s+6], 60.f)), Eo = exp2_f(z[s+9]);
      float f  = rcp_f(1.f + Ef);
      float ig = (1.f - Ec) * rcp_f((1.f + Ei) * (1.f + Ec));
      cst[s] = fmaf(f, cst[s], ig);
      float Et = exp2_f(fminf(-2.885390081777927f * cst[s], 60.f));
      hl[s] = (1.f - Et) * rcp_f((1.f + Eo) * (1.f + Et));
    }
    h[0] = qb<0x00>(hl[0]); h[1] = qb<0x55>(hl[0]); h[2] = qb<0xAA>(hl[0]); h[3] = qb<0xFF>(hl[0]);
    h[4] = qb<0x00>(hl[1]); h[5] = qb<0x55>(hl[1]); h[6] = qb<0xAA>(hl[1]); h[7] = qb<0xFF>(hl[1]);
    h[8] = qb<0x00>(hl[2]); h[9] = qb<0x55>(hl[2]);
  }
  #pragma unroll
  for (int s = 0; s < 4; ++s) {
    int j = s * 4 + sub;
    if (j < NLAB) {
      float acc = bd[j];
      #pragma unroll
      for (int k = 0; k < HID; ++k)
        acc = fmaf(h[k], Wd[k * NLAB + j], acc);
      out[(size_t)(b0 + lb) * NLAB + j] = acc;
    }
  }
}

extern "C" void kernel_launch(void* const* d_in, const int* in_sizes, int n_in,
                              void* d_out, int out_size, void* d_ws, size_t ws_size,
                              hipStream_t stream) {
  (void)in_sizes; (void)n_in; (void)out_size;
  const int*   x    = (const int*)  d_in[0];
  const float* emb  = (const float*)d_in[1];
  const float* Wx   = (const float*)d_in[2];
  const float* Wh   = (const float*)d_in[3];
  const float* bias = (const float*)d_in[4];
  const float* Wd   = (const float*)d_in[5];
  const float* bd   = (const float*)d_in[6];
  float* out = (float*)d_out;

  const size_t pbytes = (size_t)VOCAB * PROWH * sizeof(__half);   // 8 MB
  if (ws_size >= pbytes) {
    __half* P = (__half*)d_ws;
    hipLaunchKernelGGL(proj_kernel_h, dim3((VOCAB + 31) / 32), dim3(256), 0, stream,
                       emb, Wx, bias, P);
    hipLaunchKernelGGL(rnn8h_kernel, dim3(BATCH / 32), dim3(256), 0, stream,
                       x, P, Wh, Wd, bd, out);
  } else {
    hipLaunchKernelGGL(rnn_kernel_fb, dim3(BATCH / 64), dim3(256), 0, stream,
                       x, emb, Wx, Wh, bias, Wd, bd, out);
  }
}